// Round 3
// baseline (21686.792 us; speedup 1.0000x reference)
//
#include <hip/hip_runtime.h>
#include <hip/hip_bf16.h>
#include <cstddef>
#include <cstdint>

// B=32, T=2048, D=64, H=256, O=32, 4H=1024
#define BB 32
#define TT 2048
#define DD 64
#define HH 256
#define OO 32
#define NBLK 8   // blocks per layer

#define OUT_ELEMS (BB*TT*OO)
#define HN_OFF OUT_ELEMS
#define CN_OFF (HN_OFF + 2*BB*HH)

// ---------------- workspace byte offsets ----------------
// xbf2 [T][B][64] bf16 (transposed so B-frag lanes are contiguous-ish)
#define O_XBF   ((size_t)0)                     // 8,388,608 B
// h0buf [2049][32][256] bf16 : h-state of layer0 before step t
#define O_H0    ((size_t)8388608)               // 33,570,816 B
// xh1 [2049][32][512] bf16 : [t][b][0:256]=y0[t], [t][b][256:512]=h1 before step t
#define O_XH1   ((size_t)41959424)              // 67,141,632 B
// Wperm0 [1024 rows permuted][320] bf16 (cols 0:64 Wih0 | 64:320 Whh0)
#define O_WP0   ((size_t)109101056)             // 655,360 B
// Wperm1 [1024][512] bf16 (cols 0:256 Wih1 | 256:512 Whh1)
#define O_WP1   ((size_t)109756416)             // 1,048,576 B
#define O_B0    ((size_t)110804992)             // bias0 [1024] f32 (natural order)
#define O_B1    ((size_t)110809088)             // bias1 [1024] f32
#define O_WD0T  ((size_t)110813184)             // [256][256] f32 transposed
#define O_WD1T  ((size_t)111075328)
#define O_WOUT  ((size_t)111337472)             // [256][32] f32
#define O_D0    ((size_t)111370240)             // 64 flag slots x 32 ints (128B apart)
#define O_D1    ((size_t)111378432)             // 64 flag slots x 32 ints

typedef short short8 __attribute__((ext_vector_type(8)));
typedef float f32x4 __attribute__((ext_vector_type(4)));

__device__ __forceinline__ float sigm_(float x){ return 1.0f/(1.0f+__expf(-x)); }
__device__ __forceinline__ float tanhf_(float x){
    float xc = fminf(fmaxf(x, -15.0f), 15.0f);
    float e = __expf(2.0f*xc);
    return (e-1.0f)/(e+1.0f);
}
__device__ __forceinline__ unsigned short f2bf(float f){
    __hip_bfloat16 h = __float2bfloat16(f);
    return *reinterpret_cast<unsigned short*>(&h);
}
__device__ __forceinline__ unsigned int pack2(float a, float b){
    return (unsigned int)f2bf(a) | ((unsigned int)f2bf(b) << 16);
}
__device__ __forceinline__ short8 ld8(const unsigned short* p){
    return *reinterpret_cast<const short8*>(p);
}

// ---------------------------------------------------------------------------
// Prep.  Weight-row permutation for the all-4-gates-per-wave A-fragments:
//   row_local R = j*128 + hr*32 + s*16 + lrow  (j=block, hr=wave h-range)
//   gate = 2s + (lrow>>3), h = 32j + 8hr + (lrow&7), src_row = 256*gate + h
// total elems = 4194304+327680+524288+1024+1024+8192+8192+65536+65536+8192+4096
//             = 5,208,064 = 20344*256
// ---------------------------------------------------------------------------
__global__ void prep_kernel(const float* __restrict__ x, const float* __restrict__ h0,
    const float* __restrict__ Wih0, const float* __restrict__ Whh0,
    const float* __restrict__ bih0, const float* __restrict__ bhh0,
    const float* __restrict__ Wih1, const float* __restrict__ Whh1,
    const float* __restrict__ bih1, const float* __restrict__ bhh1,
    const float* __restrict__ Wd0, const float* __restrict__ Wd1,
    const float* __restrict__ Wout, char* __restrict__ ws)
{
    int i = blockIdx.x*256 + threadIdx.x;
    if (i < 4194304) {  // x [B][T][D] -> xbf2 [T][B][D] bf16
        int t = i >> 11, rem = i & 2047, b = rem >> 6, d = rem & 63;
        ((unsigned short*)(ws+O_XBF))[i] = f2bf(x[(size_t)b*131072 + t*64 + d]);
        return;
    }
    i -= 4194304;
    if (i < 327680) {   // Wperm0 [1024][320]
        int R = i / 320, k = i - R*320;
        int lrow = R & 15, s = (R>>4)&1, hr = (R>>5)&3, jj = R>>7;
        int gate = 2*s + (lrow>>3);
        int h = 32*jj + 8*hr + (lrow&7);
        int src = 256*gate + h;
        float v = (k < 64) ? Wih0[src*64 + k] : Whh0[src*256 + (k-64)];
        ((unsigned short*)(ws+O_WP0))[i] = f2bf(v);
        return;
    }
    i -= 327680;
    if (i < 524288) {   // Wperm1 [1024][512]
        int R = i >> 9, k = i & 511;
        int lrow = R & 15, s = (R>>4)&1, hr = (R>>5)&3, jj = R>>7;
        int gate = 2*s + (lrow>>3);
        int h = 32*jj + 8*hr + (lrow&7);
        int src = 256*gate + h;
        float v = (k < 256) ? Wih1[src*256 + k] : Whh1[src*256 + (k-256)];
        ((unsigned short*)(ws+O_WP1))[i] = f2bf(v);
        return;
    }
    i -= 524288;
    if (i < 1024) { ((float*)(ws+O_B0))[i] = bih0[i] + bhh0[i]; return; }
    i -= 1024;
    if (i < 1024) { ((float*)(ws+O_B1))[i] = bih1[i] + bhh1[i]; return; }
    i -= 1024;
    if (i < 8192) { ((unsigned short*)(ws+O_H0))[i] = f2bf(h0[i]); return; }   // h0buf[0]
    i -= 8192;
    if (i < 8192) {     // xh1[0][b][256+h] = h0[1][b][h]
        int b = i >> 8, h = i & 255;
        ((unsigned short*)(ws+O_XH1))[b*512 + 256 + h] = f2bf(h0[8192 + i]);
        return;
    }
    i -= 8192;
    if (i < 65536) { int o = i & 255, h = i >> 8; ((float*)(ws+O_WD0T))[i] = Wd0[o*256 + h]; return; }
    i -= 65536;
    if (i < 65536) { int o = i & 255, h = i >> 8; ((float*)(ws+O_WD1T))[i] = Wd1[o*256 + h]; return; }
    i -= 65536;
    if (i < 8192) { int o = i & 31, h = i >> 5; ((float*)(ws+O_WOUT))[i] = Wout[o*256 + h]; return; }
    i -= 8192;
    if (i < 4096) { ((int*)(ws+O_D0))[i] = 0; return; }   // D0+D1 contiguous
}

// ---------------------------------------------------------------------------
// Persistent LSTM, barrier-free per-wave dataflow.
// 8 blocks/layer x 512 threads (8 waves).  Wave (hr,bh) of block j owns
// all 4 gates for h-range [32j+8hr, +8) x batches [16bh, +16).
// A-frags (weights, permuted rows) pinned in VGPRs for all 2048 steps.
// Per wave per step: poll 64 flag slots (1/lane) -> acquire fence ->
// plain B-frag loads -> 20/32 MFMA -> shfl_xor(32) register combine ->
// agent-scope bf16x4 store -> own-slot release flag.  No LDS, no barriers.
// mfma_f32_16x16x32_bf16: A lane l -> A[row=l&15][k=(l>>4)*8+j];
//                         B lane l -> B[k][col=l&15];
//                         D lane l -> D[row=(l>>4)*4+r][col=l&15].
// ---------------------------------------------------------------------------
template<int L>
__device__ void lstm_body(int j, char* ws, const float* __restrict__ c0_in,
                          float* __restrict__ out)
{
    constexpr int KK  = L ? 512 : 320;
    constexpr int NKT = KK / 32;

    const int tid  = threadIdx.x;
    const int wv   = tid >> 6;
    const int lane = tid & 63;
    const int bh   = wv >> 2;          // batch half
    const int hr   = wv & 3;           // h-range within block slice
    const int lrow = lane & 15;
    const int q    = lane >> 4;
    const int koff = q * 8;
    const int qe   = q & 1;
    const int fb   = bh*16 + lrow;             // batch (B-frag col & combine col)
    const int hbase= 32*j + 8*hr + 4*qe;       // global h base (combine rows +r)
    const bool lo  = (lane < 32);

    const unsigned short* Wp = (const unsigned short*)(ws + (L ? O_WP1 : O_WP0));
    const float* bias = (const float*)(ws + (L ? O_B1 : O_B0));

    // A fragments: tile s=0 -> gates i,f ; tile s=1 -> gates g,o (prep-permuted)
    const int wavebase = (j*4 + hr) * 32;
    short8 a0[NKT], a1[NKT];
#pragma unroll
    for (int kk = 0; kk < NKT; ++kk) {
        a0[kk] = ld8(Wp + (size_t)(wavebase +      lrow)*KK + kk*32 + koff);
        a1[kk] = ld8(Wp + (size_t)(wavebase + 16 + lrow)*KK + kk*32 + koff);
    }

    float bi[4], bf_[4], bg[4], bo[4], c[4], hv[4];
#pragma unroll
    for (int r = 0; r < 4; ++r) {
        int hg = hbase + r;
        bi[r] = bias[hg];       bf_[r] = bias[256+hg];
        bg[r] = bias[512+hg];   bo[r]  = bias[768+hg];
        c[r]  = c0_in[(size_t)L*8192 + fb*256 + hg];
        hv[r] = 0.f;
    }

    int* d0 = (int*)(ws + O_D0);
    int* d1 = (int*)(ws + O_D1);
    int* myflag = (L ? d1 : d0) + (j*8 + wv) * 32;
    int* poll0  = d0 + lane * 32;
    int* poll1  = d1 + lane * 32;

    const unsigned short* xb = (const unsigned short*)(ws + O_XBF) + fb*64  + koff;
    const unsigned short* hb = (const unsigned short*)(ws + O_H0)  + fb*256 + koff;
    const unsigned short* xh = (const unsigned short*)(ws + O_XH1) + fb*512 + koff;

    // per-step 8B store destinations
    unsigned long long* stA;                 // lanes<32
    unsigned long long* stB = nullptr;       // lanes>=32 (L0: y0 copy)
    if (L == 0) {
        stA = (unsigned long long*)((unsigned short*)(ws + O_H0)  + (size_t)8192 + fb*256 + hbase);
        stB = (unsigned long long*)((unsigned short*)(ws + O_XH1) + (size_t)fb*512 + hbase);
    } else {
        stA = (unsigned long long*)((unsigned short*)(ws + O_XH1) + (size_t)16384 + fb*512 + 256 + hbase);
    }

    for (int t = 0; t < TT; ++t) {
        short8 b[NKT];
        if (L == 0) { b[0] = ld8(xb); b[1] = ld8(xb + 32); }   // x-part: prefetch pre-poll

        // --- poll: lane l watches slot l of each producer array ---
        {
            const int tgt0 = (L == 0) ? t : t + 1;
            int it = 0;
            while (true) {
                int v0 = __hip_atomic_load(poll0, __ATOMIC_RELAXED, __HIP_MEMORY_SCOPE_AGENT);
                bool ok = (v0 >= tgt0);
                if (L == 1) {
                    int v1 = __hip_atomic_load(poll1, __ATOMIC_RELAXED, __HIP_MEMORY_SCOPE_AGENT);
                    ok = ok && (v1 >= t);
                }
                if (__all(ok)) break;
                if (++it > (1<<17)) break;   // bug -> fail loudly, not hang
            }
            __builtin_amdgcn_fence(__ATOMIC_ACQUIRE, "agent");
        }

        // --- B fragments (fresh lines, post-fence) ---
        if (L == 0) {
#pragma unroll
            for (int kk = 0; kk < 8; ++kk) b[2+kk] = ld8(hb + 32*kk);
        } else {
#pragma unroll
            for (int kk = 0; kk < NKT; ++kk) b[kk] = ld8(xh + 32*kk);
        }

        f32x4 A0 = {0.f,0.f,0.f,0.f}, A1 = {0.f,0.f,0.f,0.f};
#pragma unroll
        for (int kk = 0; kk < NKT; ++kk) {
            A0 = __builtin_amdgcn_mfma_f32_16x16x32_bf16(a0[kk], b[kk], A0, 0,0,0);
            A1 = __builtin_amdgcn_mfma_f32_16x16x32_bf16(a1[kk], b[kk], A1, 0,0,0);
        }

        // --- register combine: swap lane<->lane+32 to pair (i,f) and (g,o) ---
#pragma unroll
        for (int r = 0; r < 4; ++r) {
            float x0 = A0[r], y0 = __shfl_xor(x0, 32, 64);
            float x1 = A1[r], y1 = __shfl_xor(x1, 32, 64);
            float gi = (lo ? x0 : y0) + bi[r];
            float gf = (lo ? y0 : x0) + bf_[r];
            float gg = (lo ? x1 : y1) + bg[r];
            float go = (lo ? y1 : x1) + bo[r];
            float iv = sigm_(gi), fv = sigm_(gf), gv = tanhf_(gg), ov = sigm_(go);
            c[r]  = fv*c[r] + iv*gv;
            hv[r] = ov * tanhf_(c[r]);
        }

        unsigned long long w =
            (unsigned long long)pack2(hv[0], hv[1]) |
            ((unsigned long long)pack2(hv[2], hv[3]) << 32);

        if (L == 0) {
            if (lo) __hip_atomic_store(stA, w, __ATOMIC_RELAXED, __HIP_MEMORY_SCOPE_AGENT);
            else    __hip_atomic_store(stB, w, __ATOMIC_RELAXED, __HIP_MEMORY_SCOPE_AGENT);
        } else {
            if (lo) __hip_atomic_store(stA, w, __ATOMIC_RELAXED, __HIP_MEMORY_SCOPE_AGENT);
        }

        if (lane == 0)   // release waits the whole wave's vmcnt -> h visible first
            __hip_atomic_store(myflag, t+1, __ATOMIC_RELEASE, __HIP_MEMORY_SCOPE_AGENT);

        xb += 2048; hb += 8192; xh += 16384;
        stA += (L ? 4096 : 2048);           // ull units: 32KB / 16KB per t
        if (L == 0) stB += 4096;
    }

    if (lo) {
#pragma unroll
        for (int r = 0; r < 4; ++r) {
            out[HN_OFF + (size_t)L*8192 + fb*256 + hbase + r] = hv[r];
            out[CN_OFF + (size_t)L*8192 + fb*256 + hbase + r] = c[r];
        }
    }
}

__global__ __launch_bounds__(512, 2) void lstm_fused(char* ws,
                                                     const float* __restrict__ c0_in,
                                                     float* __restrict__ out)
{
    if (blockIdx.x < NBLK) lstm_body<0>(blockIdx.x, ws, c0_in, out);
    else                   lstm_body<1>(blockIdx.x - NBLK, ws, c0_in, out);
}

// ---------------------------------------------------------------------------
// Fused dense head (reads y1 = xh1[t+1][b][256:512] bf16).
// ---------------------------------------------------------------------------
__global__ __launch_bounds__(256) void head_kernel(const char* __restrict__ ws,
    const float* __restrict__ bd0, const float* __restrict__ bd1,
    const float* __restrict__ bout, float* __restrict__ out)
{
    const __hip_bfloat16* xh1 = (const __hip_bfloat16*)(ws + O_XH1);
    const float* Wd0T  = (const float*)(ws + O_WD0T);
    const float* Wd1T  = (const float*)(ws + O_WD1T);
    const float* WoutT = (const float*)(ws + O_WOUT);

    __shared__ float buf0[16][256];
    __shared__ float buf1[16][256];
    const int row0 = blockIdx.x * 16;
    const int tid = threadIdx.x;

#pragma unroll
    for (int i = 0; i < 16; ++i) {
        int r = row0 + i;
        int b = r >> 11, t = r & 2047;
        buf0[i][tid] = __bfloat162float(xh1[(size_t)(t+1)*16384 + b*512 + 256 + tid]);
    }
    __syncthreads();

    {   // stage 1: Linear+ReLU
        float acc[16];
        float bv = bd0[tid];
#pragma unroll
        for (int r = 0; r < 16; ++r) acc[r] = bv;
        for (int h = 0; h < 256; ++h) {
            float w = Wd0T[h*256 + tid];
#pragma unroll
            for (int r = 0; r < 16; ++r) acc[r] += w * buf0[r][h];
        }
        __syncthreads();
#pragma unroll
        for (int r = 0; r < 16; ++r) buf1[r][tid] = fmaxf(acc[r], 0.0f);
    }
    __syncthreads();

    {   // stage 2: Linear+ReLU
        float acc[16];
        float bv = bd1[tid];
#pragma unroll
        for (int r = 0; r < 16; ++r) acc[r] = bv;
        for (int h = 0; h < 256; ++h) {
            float w = Wd1T[h*256 + tid];
#pragma unroll
            for (int r = 0; r < 16; ++r) acc[r] += w * buf1[r][h];
        }
        __syncthreads();
#pragma unroll
        for (int r = 0; r < 16; ++r) buf0[r][tid] = fmaxf(acc[r], 0.0f);
    }
    __syncthreads();

    {   // stage 3: output Linear
        const int o = tid & 31;
        const int rr = tid >> 5;
        float a0 = bout[o], a1 = bout[o];
        for (int h = 0; h < 256; ++h) {
            float w = WoutT[h*32 + o];
            a0 += w * buf0[rr*2 + 0][h];
            a1 += w * buf0[rr*2 + 1][h];
        }
        out[(size_t)(row0 + rr*2 + 0)*32 + o] = a0;
        out[(size_t)(row0 + rr*2 + 1)*32 + o] = a1;
    }
}

// ---------------------------------------------------------------------------
extern "C" void kernel_launch(void* const* d_in, const int* in_sizes, int n_in,
                              void* d_out, int out_size, void* d_ws, size_t ws_size,
                              hipStream_t stream) {
    const float* x    = (const float*)d_in[0];
    const float* h0   = (const float*)d_in[1];
    const float* c0   = (const float*)d_in[2];
    const float* Wih0 = (const float*)d_in[3];
    const float* Whh0 = (const float*)d_in[4];
    const float* bih0 = (const float*)d_in[5];
    const float* bhh0 = (const float*)d_in[6];
    const float* Wih1 = (const float*)d_in[7];
    const float* Whh1 = (const float*)d_in[8];
    const float* bih1 = (const float*)d_in[9];
    const float* bhh1 = (const float*)d_in[10];
    const float* Wd0  = (const float*)d_in[11];
    const float* bd0  = (const float*)d_in[12];
    const float* Wd1  = (const float*)d_in[13];
    const float* bd1  = (const float*)d_in[14];
    const float* Wout = (const float*)d_in[15];
    const float* bout = (const float*)d_in[16];

    char* ws = (char*)d_ws;
    float* out = (float*)d_out;

    prep_kernel<<<20344, 256, 0, stream>>>(x, h0, Wih0, Whh0, bih0, bhh0,
                                           Wih1, Whh1, bih1, bhh1,
                                           Wd0, Wd1, Wout, ws);
    lstm_fused<<<2*NBLK, 512, 0, stream>>>(ws, c0, out);
    head_kernel<<<4096, 256, 0, stream>>>(ws, bd0, bd1, bout, out);
}

// Round 4
// 12419.349 us; speedup vs baseline: 1.7462x; 1.7462x over previous
//
#include <hip/hip_runtime.h>
#include <hip/hip_bf16.h>
#include <cstddef>
#include <cstdint>

// B=32, T=2048, D=64, H=256, O=32, 4H=1024
#define BB 32
#define TT 2048
#define DD 64
#define HH 256
#define OO 32
#define NBLK 8   // blocks per layer

#define OUT_ELEMS (BB*TT*OO)
#define HN_OFF OUT_ELEMS
#define CN_OFF (HN_OFF + 2*BB*HH)

// ---------------- workspace byte offsets ----------------
// xbf2 [T][B][64] bf16
#define O_XBF   ((size_t)0)                     // 8,388,608 B
// h0buf [2049][32][256] bf16 : h-state of layer0 before step t
#define O_H0    ((size_t)8388608)               // 33,570,816 B
// xh1 [2049][32][512] bf16 : [t][b][0:256]=y0[t], [t][b][256:512]=h1 before step t
#define O_XH1   ((size_t)41959424)              // 67,141,632 B
// Wperm0 [1024 rows permuted][320] bf16 (cols 0:64 Wih0 | 64:320 Whh0)
#define O_WP0   ((size_t)109101056)             // 655,360 B
// Wperm1 [1024][512] bf16 (cols 0:256 Wih1 | 256:512 Whh1)
#define O_WP1   ((size_t)109756416)             // 1,048,576 B
#define O_B0    ((size_t)110804992)             // bias0 [1024] f32
#define O_B1    ((size_t)110809088)             // bias1 [1024] f32
#define O_WD0T  ((size_t)110813184)             // [256][256] f32 transposed
#define O_WD1T  ((size_t)111075328)
#define O_WOUT  ((size_t)111337472)             // [256][32] f32
#define O_D0    ((size_t)111370240)             // flags layer0: int[8] (one 64B line)
#define O_D1    (O_D0 + 256)                    // flags layer1: int[8] (separate line)
// prep zeroes 16KB starting at O_D0 (covers both flag lines)

typedef short short8 __attribute__((ext_vector_type(8)));
typedef float f32x4 __attribute__((ext_vector_type(4)));

__device__ __forceinline__ float sigm_(float x){ return 1.0f/(1.0f+__expf(-x)); }
__device__ __forceinline__ float tanhf_(float x){
    float xc = fminf(fmaxf(x, -15.0f), 15.0f);
    float e = __expf(2.0f*xc);
    return (e-1.0f)/(e+1.0f);
}
__device__ __forceinline__ unsigned short f2bf(float f){
    __hip_bfloat16 h = __float2bfloat16(f);
    return *reinterpret_cast<unsigned short*>(&h);
}
__device__ __forceinline__ unsigned int pack2(float a, float b){
    return (unsigned int)f2bf(a) | ((unsigned int)f2bf(b) << 16);
}
__device__ __forceinline__ short8 ld8(const unsigned short* p){
    return *reinterpret_cast<const short8*>(p);
}

// Poll one 64B flag line: lanes 0..7 watch flags[0..7] (one LLC transaction
// per round).  No acquire fence needed: all data buffers are monotonic (fresh
// addresses each step -> no stale L1/L2 lines), and wave in-order issue after
// the dependent branch orders subsequent loads behind the observed flag.
__device__ __forceinline__ void pollLine(const int* flags, int tgt, int lane){
    int it = 0;
    while (true) {
        int v = tgt;
        if (lane < NBLK)
            v = __hip_atomic_load(flags + lane, __ATOMIC_RELAXED, __HIP_MEMORY_SCOPE_AGENT);
        if (__all(v >= tgt)) break;
        if (++it > (1<<18)) break;   // bug -> wrong output, not a hang
    }
    asm volatile("" ::: "memory");   // compiler ordering only
}

// ---------------------------------------------------------------------------
// Prep (identical layout math to round 3; only flag zeroing region reused).
// ---------------------------------------------------------------------------
__global__ void prep_kernel(const float* __restrict__ x, const float* __restrict__ h0,
    const float* __restrict__ Wih0, const float* __restrict__ Whh0,
    const float* __restrict__ bih0, const float* __restrict__ bhh0,
    const float* __restrict__ Wih1, const float* __restrict__ Whh1,
    const float* __restrict__ bih1, const float* __restrict__ bhh1,
    const float* __restrict__ Wd0, const float* __restrict__ Wd1,
    const float* __restrict__ Wout, char* __restrict__ ws)
{
    int i = blockIdx.x*256 + threadIdx.x;
    if (i < 4194304) {  // x [B][T][D] -> xbf2 [T][B][D] bf16
        int t = i >> 11, rem = i & 2047, b = rem >> 6, d = rem & 63;
        ((unsigned short*)(ws+O_XBF))[i] = f2bf(x[(size_t)b*131072 + t*64 + d]);
        return;
    }
    i -= 4194304;
    if (i < 327680) {   // Wperm0 [1024][320]
        int R = i / 320, k = i - R*320;
        int lrow = R & 15, s = (R>>4)&1, hr = (R>>5)&3, jj = R>>7;
        int gate = 2*s + (lrow>>3);
        int h = 32*jj + 8*hr + (lrow&7);
        int src = 256*gate + h;
        float v = (k < 64) ? Wih0[src*64 + k] : Whh0[src*256 + (k-64)];
        ((unsigned short*)(ws+O_WP0))[i] = f2bf(v);
        return;
    }
    i -= 327680;
    if (i < 524288) {   // Wperm1 [1024][512]
        int R = i >> 9, k = i & 511;
        int lrow = R & 15, s = (R>>4)&1, hr = (R>>5)&3, jj = R>>7;
        int gate = 2*s + (lrow>>3);
        int h = 32*jj + 8*hr + (lrow&7);
        int src = 256*gate + h;
        float v = (k < 256) ? Wih1[src*256 + k] : Whh1[src*256 + (k-256)];
        ((unsigned short*)(ws+O_WP1))[i] = f2bf(v);
        return;
    }
    i -= 524288;
    if (i < 1024) { ((float*)(ws+O_B0))[i] = bih0[i] + bhh0[i]; return; }
    i -= 1024;
    if (i < 1024) { ((float*)(ws+O_B1))[i] = bih1[i] + bhh1[i]; return; }
    i -= 1024;
    if (i < 8192) { ((unsigned short*)(ws+O_H0))[i] = f2bf(h0[i]); return; }   // h0buf[0]
    i -= 8192;
    if (i < 8192) {     // xh1[0][b][256+h] = h0[1][b][h]
        int b = i >> 8, h = i & 255;
        ((unsigned short*)(ws+O_XH1))[b*512 + 256 + h] = f2bf(h0[8192 + i]);
        return;
    }
    i -= 8192;
    if (i < 65536) { int o = i & 255, h = i >> 8; ((float*)(ws+O_WD0T))[i] = Wd0[o*256 + h]; return; }
    i -= 65536;
    if (i < 65536) { int o = i & 255, h = i >> 8; ((float*)(ws+O_WD1T))[i] = Wd1[o*256 + h]; return; }
    i -= 65536;
    if (i < 8192) { int o = i & 31, h = i >> 5; ((float*)(ws+O_WOUT))[i] = Wout[o*256 + h]; return; }
    i -= 8192;
    if (i < 4096) { ((int*)(ws+O_D0))[i] = 0; return; }   // zero flag region (16KB)
}

// ---------------------------------------------------------------------------
// Persistent LSTM.  8 blocks/layer x 512 threads (8 waves).  Wave (hr,bh) of
// block j owns all 4 gates for h-range [32j+8hr,+8) x batches [16bh,+16).
// A-frags pinned in VGPRs.  Per step: [pre-poll MFMAs on already-available
// inputs] -> poll one flag line -> B-frag loads -> MFMAs -> shfl_xor register
// gate-combine -> sc1 stores -> __syncthreads (drains vmcnt) -> tid0 flag.
// mfma_f32_16x16x32_bf16: A lane l -> A[row=l&15][k=(l>>4)*8+j];
//                         B lane l -> B[k][col=l&15];
//                         D lane l -> D[row=(l>>4)*4+r][col=l&15].
// ---------------------------------------------------------------------------
template<int L>
__device__ void lstm_body(int j, char* ws, const float* __restrict__ c0_in,
                          float* __restrict__ out)
{
    constexpr int KK  = L ? 512 : 320;
    constexpr int NKT = KK / 32;

    const int tid  = threadIdx.x;
    const int wv   = tid >> 6;
    const int lane = tid & 63;
    const int bh   = wv >> 2;          // batch half
    const int hr   = wv & 3;           // h-range within block slice
    const int lrow = lane & 15;
    const int q    = lane >> 4;
    const int koff = q * 8;
    const int qe   = q & 1;
    const int fb   = bh*16 + lrow;             // batch (B-frag col & combine col)
    const int hbase= 32*j + 8*hr + 4*qe;       // global h base (combine rows +r)
    const bool lo  = (lane < 32);

    const unsigned short* Wp = (const unsigned short*)(ws + (L ? O_WP1 : O_WP0));
    const float* bias = (const float*)(ws + (L ? O_B1 : O_B0));

    // A fragments: tile s=0 -> gates i,f ; tile s=1 -> gates g,o
    const int wavebase = (j*4 + hr) * 32;
    short8 a0[NKT], a1[NKT];
#pragma unroll
    for (int kk = 0; kk < NKT; ++kk) {
        a0[kk] = ld8(Wp + (size_t)(wavebase +      lrow)*KK + kk*32 + koff);
        a1[kk] = ld8(Wp + (size_t)(wavebase + 16 + lrow)*KK + kk*32 + koff);
    }

    float bi[4], bf_[4], bg[4], bo[4], c[4], hv[4];
#pragma unroll
    for (int r = 0; r < 4; ++r) {
        int hg = hbase + r;
        bi[r] = bias[hg];       bf_[r] = bias[256+hg];
        bg[r] = bias[512+hg];   bo[r]  = bias[768+hg];
        c[r]  = c0_in[(size_t)L*8192 + fb*256 + hg];
        hv[r] = 0.f;
    }

    int* flags0 = (int*)(ws + O_D0);
    int* flags1 = (int*)(ws + O_D1);
    int* myflag = (L ? flags1 : flags0) + j;

    const unsigned short* xb = (const unsigned short*)(ws + O_XBF) + fb*64  + koff;
    const unsigned short* hb = (const unsigned short*)(ws + O_H0)  + fb*256 + koff;
    const unsigned short* xh = (const unsigned short*)(ws + O_XH1) + fb*512 + koff;

    // per-step 8B store destinations (agent-scope sc1 -> LLC)
    unsigned long long* stA;                 // lanes<32
    unsigned long long* stB = nullptr;       // lanes>=32 (L0: y0 copy)
    if (L == 0) {
        stA = (unsigned long long*)((unsigned short*)(ws + O_H0)  + (size_t)8192 + fb*256 + hbase);
        stB = (unsigned long long*)((unsigned short*)(ws + O_XH1) + (size_t)fb*512 + hbase);
    } else {
        stA = (unsigned long long*)((unsigned short*)(ws + O_XH1) + (size_t)16384 + fb*512 + 256 + hbase);
    }

    for (int t = 0; t < TT; ++t) {
        f32x4 A0 = {0.f,0.f,0.f,0.f}, A1 = {0.f,0.f,0.f,0.f};

        if (L == 0) {
            // x-part: available since prep -> load + 4 MFMAs BEFORE the poll
            short8 bx0 = ld8(xb), bx1 = ld8(xb + 32);
            A0 = __builtin_amdgcn_mfma_f32_16x16x32_bf16(a0[0], bx0, A0, 0,0,0);
            A1 = __builtin_amdgcn_mfma_f32_16x16x32_bf16(a1[0], bx0, A1, 0,0,0);
            A0 = __builtin_amdgcn_mfma_f32_16x16x32_bf16(a0[1], bx1, A0, 0,0,0);
            A1 = __builtin_amdgcn_mfma_f32_16x16x32_bf16(a1[1], bx1, A1, 0,0,0);

            pollLine(flags0, t, lane);           // h0[t] ready (all 8 slices)

            short8 b[8];
#pragma unroll
            for (int kk = 0; kk < 8; ++kk) b[kk] = ld8(hb + 32*kk);
#pragma unroll
            for (int kk = 0; kk < 8; ++kk) {
                A0 = __builtin_amdgcn_mfma_f32_16x16x32_bf16(a0[2+kk], b[kk], A0, 0,0,0);
                A1 = __builtin_amdgcn_mfma_f32_16x16x32_bf16(a1[2+kk], b[kk], A1, 0,0,0);
            }
        } else {
            // y0[t] (produced by layer0 step t, usually already flagged):
            pollLine(flags0, t+1, lane);
            short8 b[8];
#pragma unroll
            for (int kk = 0; kk < 8; ++kk) b[kk] = ld8(xh + 32*kk);        // k 0..255
#pragma unroll
            for (int kk = 0; kk < 8; ++kk) {
                A0 = __builtin_amdgcn_mfma_f32_16x16x32_bf16(a0[kk], b[kk], A0, 0,0,0);
                A1 = __builtin_amdgcn_mfma_f32_16x16x32_bf16(a1[kk], b[kk], A1, 0,0,0);
            }
            // h1 self-dependency (the real critical chain):
            pollLine(flags1, t, lane);
#pragma unroll
            for (int kk = 0; kk < 8; ++kk) b[kk] = ld8(xh + 256 + 32*kk);  // k 256..511
#pragma unroll
            for (int kk = 0; kk < 8; ++kk) {
                A0 = __builtin_amdgcn_mfma_f32_16x16x32_bf16(a0[8+kk], b[kk], A0, 0,0,0);
                A1 = __builtin_amdgcn_mfma_f32_16x16x32_bf16(a1[8+kk], b[kk], A1, 0,0,0);
            }
        }

        // --- register combine: swap lane<->lane+32 pairs (i,f) and (g,o) ---
#pragma unroll
        for (int r = 0; r < 4; ++r) {
            float x0 = A0[r], y0 = __shfl_xor(x0, 32, 64);
            float x1 = A1[r], y1 = __shfl_xor(x1, 32, 64);
            float gi = (lo ? x0 : y0) + bi[r];
            float gf = (lo ? y0 : x0) + bf_[r];
            float gg = (lo ? x1 : y1) + bg[r];
            float go = (lo ? y1 : x1) + bo[r];
            float iv = sigm_(gi), fv = sigm_(gf), gv = tanhf_(gg), ov = sigm_(go);
            c[r]  = fv*c[r] + iv*gv;
            hv[r] = ov * tanhf_(c[r]);
        }

        unsigned long long w =
            (unsigned long long)pack2(hv[0], hv[1]) |
            ((unsigned long long)pack2(hv[2], hv[3]) << 32);

        if (L == 0) {
            if (lo) __hip_atomic_store(stA, w, __ATOMIC_RELAXED, __HIP_MEMORY_SCOPE_AGENT);
            else    __hip_atomic_store(stB, w, __ATOMIC_RELAXED, __HIP_MEMORY_SCOPE_AGENT);
        } else {
            if (lo) __hip_atomic_store(stA, w, __ATOMIC_RELAXED, __HIP_MEMORY_SCOPE_AGENT);
        }

        // barrier drains every wave's vmcnt (stores LLC-visible) before flag
        __syncthreads();
        if (tid == 0)
            __hip_atomic_store(myflag, t+1, __ATOMIC_RELAXED, __HIP_MEMORY_SCOPE_AGENT);

        xb += 2048; hb += 8192; xh += 16384;
        stA += (L ? 4096 : 2048);
        if (L == 0) stB += 4096;
    }

    if (lo) {
#pragma unroll
        for (int r = 0; r < 4; ++r) {
            out[HN_OFF + (size_t)L*8192 + fb*256 + hbase + r] = hv[r];
            out[CN_OFF + (size_t)L*8192 + fb*256 + hbase + r] = c[r];
        }
    }
}

__global__ __launch_bounds__(512, 2) void lstm_fused(char* ws,
                                                     const float* __restrict__ c0_in,
                                                     float* __restrict__ out)
{
    if (blockIdx.x < NBLK) lstm_body<0>(blockIdx.x, ws, c0_in, out);
    else                   lstm_body<1>(blockIdx.x - NBLK, ws, c0_in, out);
}

// ---------------------------------------------------------------------------
// Fused dense head (reads y1 = xh1[t+1][b][256:512] bf16).
// ---------------------------------------------------------------------------
__global__ __launch_bounds__(256) void head_kernel(const char* __restrict__ ws,
    const float* __restrict__ bd0, const float* __restrict__ bd1,
    const float* __restrict__ bout, float* __restrict__ out)
{
    const __hip_bfloat16* xh1 = (const __hip_bfloat16*)(ws + O_XH1);
    const float* Wd0T  = (const float*)(ws + O_WD0T);
    const float* Wd1T  = (const float*)(ws + O_WD1T);
    const float* WoutT = (const float*)(ws + O_WOUT);

    __shared__ float buf0[16][256];
    __shared__ float buf1[16][256];
    const int row0 = blockIdx.x * 16;
    const int tid = threadIdx.x;

#pragma unroll
    for (int i = 0; i < 16; ++i) {
        int r = row0 + i;
        int b = r >> 11, t = r & 2047;
        buf0[i][tid] = __bfloat162float(xh1[(size_t)(t+1)*16384 + b*512 + 256 + tid]);
    }
    __syncthreads();

    {   // stage 1: Linear+ReLU
        float acc[16];
        float bv = bd0[tid];
#pragma unroll
        for (int r = 0; r < 16; ++r) acc[r] = bv;
        for (int h = 0; h < 256; ++h) {
            float w = Wd0T[h*256 + tid];
#pragma unroll
            for (int r = 0; r < 16; ++r) acc[r] += w * buf0[r][h];
        }
        __syncthreads();
#pragma unroll
        for (int r = 0; r < 16; ++r) buf1[r][tid] = fmaxf(acc[r], 0.0f);
    }
    __syncthreads();

    {   // stage 2: Linear+ReLU
        float acc[16];
        float bv = bd1[tid];
#pragma unroll
        for (int r = 0; r < 16; ++r) acc[r] = bv;
        for (int h = 0; h < 256; ++h) {
            float w = Wd1T[h*256 + tid];
#pragma unroll
            for (int r = 0; r < 16; ++r) acc[r] += w * buf1[r][h];
        }
        __syncthreads();
#pragma unroll
        for (int r = 0; r < 16; ++r) buf0[r][tid] = fmaxf(acc[r], 0.0f);
    }
    __syncthreads();

    {   // stage 3: output Linear
        const int o = tid & 31;
        const int rr = tid >> 5;
        float a0 = bout[o], a1 = bout[o];
        for (int h = 0; h < 256; ++h) {
            float w = WoutT[h*32 + o];
            a0 += w * buf0[rr*2 + 0][h];
            a1 += w * buf0[rr*2 + 1][h];
        }
        out[(size_t)(row0 + rr*2 + 0)*32 + o] = a0;
        out[(size_t)(row0 + rr*2 + 1)*32 + o] = a1;
    }
}

// ---------------------------------------------------------------------------
extern "C" void kernel_launch(void* const* d_in, const int* in_sizes, int n_in,
                              void* d_out, int out_size, void* d_ws, size_t ws_size,
                              hipStream_t stream) {
    const float* x    = (const float*)d_in[0];
    const float* h0   = (const float*)d_in[1];
    const float* c0   = (const float*)d_in[2];
    const float* Wih0 = (const float*)d_in[3];
    const float* Whh0 = (const float*)d_in[4];
    const float* bih0 = (const float*)d_in[5];
    const float* bhh0 = (const float*)d_in[6];
    const float* Wih1 = (const float*)d_in[7];
    const float* Whh1 = (const float*)d_in[8];
    const float* bih1 = (const float*)d_in[9];
    const float* bhh1 = (const float*)d_in[10];
    const float* Wd0  = (const float*)d_in[11];
    const float* bd0  = (const float*)d_in[12];
    const float* Wd1  = (const float*)d_in[13];
    const float* bd1  = (const float*)d_in[14];
    const float* Wout = (const float*)d_in[15];
    const float* bout = (const float*)d_in[16];

    char* ws = (char*)d_ws;
    float* out = (float*)d_out;

    prep_kernel<<<20344, 256, 0, stream>>>(x, h0, Wih0, Whh0, bih0, bhh0,
                                           Wih1, Whh1, bih1, bhh1,
                                           Wd0, Wd1, Wout, ws);
    lstm_fused<<<2*NBLK, 512, 0, stream>>>(ws, c0, out);
    head_kernel<<<4096, 256, 0, stream>>>(ws, bd0, bd1, bout, out);
}

// Round 5
// 12099.222 us; speedup vs baseline: 1.7924x; 1.0265x over previous
//
#include <hip/hip_runtime.h>
#include <hip/hip_bf16.h>
#include <cstddef>
#include <cstdint>

// B=32, T=2048, D=64, H=256, O=32, 4H=1024
#define BB 32
#define TT 2048
#define DD 64
#define HH 256
#define OO 32
#define NBLK 8   // blocks per layer

#define OUT_ELEMS (BB*TT*OO)
#define HN_OFF OUT_ELEMS
#define CN_OFF (HN_OFF + 2*BB*HH)

// ---------------- workspace byte offsets ----------------
// xbf2 [T][B][64] bf16
#define O_XBF   ((size_t)0)                     // 8,388,608 B
// h0buf [2049][32][256] bf16 : h-state of layer0 before step t
#define O_H0    ((size_t)8388608)               // 33,570,816 B
// xh1 [2049][32][512] bf16 : [t][b][0:256]=y0[t], [t][b][256:512]=h1 before step t
#define O_XH1   ((size_t)41959424)              // 67,141,632 B
// Wperm0 [1024 rows permuted][320] bf16 (cols 0:64 Wih0 | 64:320 Whh0)
#define O_WP0   ((size_t)109101056)             // 655,360 B
// Wperm1 [1024][512] bf16 (cols 0:256 Wih1 | 256:512 Whh1)
#define O_WP1   ((size_t)109756416)             // 1,048,576 B
#define O_B0    ((size_t)110804992)             // bias0 [1024] f32
#define O_B1    ((size_t)110809088)             // bias1 [1024] f32
#define O_WD0T  ((size_t)110813184)             // [256][256] f32 transposed
#define O_WD1T  ((size_t)111075328)
#define O_WOUT  ((size_t)111337472)             // [256][32] f32
#define O_D0    ((size_t)111370240)             // flags layer0: int[8] (one 64B line)
#define O_D1    (O_D0 + 256)                    // flags layer1: int[8] (separate line)
// prep zeroes 16KB starting at O_D0 (covers both flag lines)

typedef short short8 __attribute__((ext_vector_type(8)));
typedef float f32x4 __attribute__((ext_vector_type(4)));

__device__ __forceinline__ float sigm_(float x){ return 1.0f/(1.0f+__expf(-x)); }
__device__ __forceinline__ float tanhf_(float x){
    float xc = fminf(fmaxf(x, -15.0f), 15.0f);
    float e = __expf(2.0f*xc);
    return (e-1.0f)/(e+1.0f);
}
__device__ __forceinline__ unsigned short f2bf(float f){
    __hip_bfloat16 h = __float2bfloat16(f);
    return *reinterpret_cast<unsigned short*>(&h);
}
__device__ __forceinline__ unsigned int pack2(float a, float b){
    return (unsigned int)f2bf(a) | ((unsigned int)f2bf(b) << 16);
}
__device__ __forceinline__ short8 ld8(const unsigned short* p){
    return *reinterpret_cast<const short8*>(p);
}

// Single-poller primitives: called by wave 0 only; the rest of the block
// waits at the following __syncthreads().  One LLC transaction per round,
// s_sleep backoff after a failed check.  Capped so a bug fails validation
// instead of hanging.  No acquire fence: data buffers are monotonic (fresh
// addresses each step -> no stale L1/L2 lines); the asm is compiler-ordering.
__device__ __forceinline__ void pollLine(const int* flags, int tgt, int lane){
    int it = 0;
    while (true) {
        int v = tgt;
        if (lane < NBLK)
            v = __hip_atomic_load(flags + lane, __ATOMIC_RELAXED, __HIP_MEMORY_SCOPE_AGENT);
        if (__all(v >= tgt)) break;
        __builtin_amdgcn_s_sleep(1);
        if (++it > (1<<16)) break;   // bug -> wrong output, not a hang
    }
    asm volatile("" ::: "memory");
}

// Lane-split poll of two flag lines in one load per round:
// lanes 0..7 watch f0[lane] >= t0, lanes 8..15 watch f1[lane-8] >= t1.
__device__ __forceinline__ void pollTwo(const int* f0, int t0,
                                        const int* f1, int t1, int lane){
    const int* p = (lane < 8) ? (f0 + lane) : (f1 + (lane - 8));
    const int tgt = (lane < 8) ? t0 : t1;
    int it = 0;
    while (true) {
        int v = tgt;
        if (lane < 16)
            v = __hip_atomic_load(p, __ATOMIC_RELAXED, __HIP_MEMORY_SCOPE_AGENT);
        if (__all(v >= tgt)) break;
        __builtin_amdgcn_s_sleep(1);
        if (++it > (1<<16)) break;
    }
    asm volatile("" ::: "memory");
}

// ---------------------------------------------------------------------------
// Prep (identical to round 4).
// ---------------------------------------------------------------------------
__global__ void prep_kernel(const float* __restrict__ x, const float* __restrict__ h0,
    const float* __restrict__ Wih0, const float* __restrict__ Whh0,
    const float* __restrict__ bih0, const float* __restrict__ bhh0,
    const float* __restrict__ Wih1, const float* __restrict__ Whh1,
    const float* __restrict__ bih1, const float* __restrict__ bhh1,
    const float* __restrict__ Wd0, const float* __restrict__ Wd1,
    const float* __restrict__ Wout, char* __restrict__ ws)
{
    int i = blockIdx.x*256 + threadIdx.x;
    if (i < 4194304) {  // x [B][T][D] -> xbf2 [T][B][D] bf16
        int t = i >> 11, rem = i & 2047, b = rem >> 6, d = rem & 63;
        ((unsigned short*)(ws+O_XBF))[i] = f2bf(x[(size_t)b*131072 + t*64 + d]);
        return;
    }
    i -= 4194304;
    if (i < 327680) {   // Wperm0 [1024][320]
        int R = i / 320, k = i - R*320;
        int lrow = R & 15, s = (R>>4)&1, hr = (R>>5)&3, jj = R>>7;
        int gate = 2*s + (lrow>>3);
        int h = 32*jj + 8*hr + (lrow&7);
        int src = 256*gate + h;
        float v = (k < 64) ? Wih0[src*64 + k] : Whh0[src*256 + (k-64)];
        ((unsigned short*)(ws+O_WP0))[i] = f2bf(v);
        return;
    }
    i -= 327680;
    if (i < 524288) {   // Wperm1 [1024][512]
        int R = i >> 9, k = i & 511;
        int lrow = R & 15, s = (R>>4)&1, hr = (R>>5)&3, jj = R>>7;
        int gate = 2*s + (lrow>>3);
        int h = 32*jj + 8*hr + (lrow&7);
        int src = 256*gate + h;
        float v = (k < 256) ? Wih1[src*256 + k] : Whh1[src*256 + (k-256)];
        ((unsigned short*)(ws+O_WP1))[i] = f2bf(v);
        return;
    }
    i -= 524288;
    if (i < 1024) { ((float*)(ws+O_B0))[i] = bih0[i] + bhh0[i]; return; }
    i -= 1024;
    if (i < 1024) { ((float*)(ws+O_B1))[i] = bih1[i] + bhh1[i]; return; }
    i -= 1024;
    if (i < 8192) { ((unsigned short*)(ws+O_H0))[i] = f2bf(h0[i]); return; }   // h0buf[0]
    i -= 8192;
    if (i < 8192) {     // xh1[0][b][256+h] = h0[1][b][h]
        int b = i >> 8, h = i & 255;
        ((unsigned short*)(ws+O_XH1))[b*512 + 256 + h] = f2bf(h0[8192 + i]);
        return;
    }
    i -= 8192;
    if (i < 65536) { int o = i & 255, h = i >> 8; ((float*)(ws+O_WD0T))[i] = Wd0[o*256 + h]; return; }
    i -= 65536;
    if (i < 65536) { int o = i & 255, h = i >> 8; ((float*)(ws+O_WD1T))[i] = Wd1[o*256 + h]; return; }
    i -= 65536;
    if (i < 8192) { int o = i & 31, h = i >> 5; ((float*)(ws+O_WOUT))[i] = Wout[o*256 + h]; return; }
    i -= 8192;
    if (i < 4096) { ((int*)(ws+O_D0))[i] = 0; return; }   // zero flag region (16KB)
}

// ---------------------------------------------------------------------------
// Persistent LSTM.  8 blocks/layer x 512 threads (8 waves).  Wave (hr,bh) of
// block j owns all 4 gates for h-range [32j+8hr,+8) x batches [16bh,+16).
// A-frags pinned in VGPRs.  Per step: [pre-poll MFMAs on static inputs] ->
// wave0 polls flag line(s) -> __syncthreads broadcast -> B-frag loads ->
// MFMAs -> shfl_xor register gate-combine -> sc1 stores -> __syncthreads
// (drains vmcnt) -> tid0 flag.
// mfma_f32_16x16x32_bf16: A lane l -> A[row=l&15][k=(l>>4)*8+j];
//                         B lane l -> B[k][col=l&15];
//                         D lane l -> D[row=(l>>4)*4+r][col=l&15].
// ---------------------------------------------------------------------------
template<int L>
__device__ void lstm_body(int j, char* ws, const float* __restrict__ c0_in,
                          float* __restrict__ out)
{
    constexpr int KK  = L ? 512 : 320;
    constexpr int NKT = KK / 32;

    const int tid  = threadIdx.x;
    const int wv   = tid >> 6;
    const int lane = tid & 63;
    const int bh   = wv >> 2;          // batch half
    const int hr   = wv & 3;           // h-range within block slice
    const int lrow = lane & 15;
    const int q    = lane >> 4;
    const int koff = q * 8;
    const int qe   = q & 1;
    const int fb   = bh*16 + lrow;             // batch (B-frag col & combine col)
    const int hbase= 32*j + 8*hr + 4*qe;       // global h base (combine rows +r)
    const bool lo  = (lane < 32);

    const unsigned short* Wp = (const unsigned short*)(ws + (L ? O_WP1 : O_WP0));
    const float* bias = (const float*)(ws + (L ? O_B1 : O_B0));

    // A fragments: tile s=0 -> gates i,f ; tile s=1 -> gates g,o
    const int wavebase = (j*4 + hr) * 32;
    short8 a0[NKT], a1[NKT];
#pragma unroll
    for (int kk = 0; kk < NKT; ++kk) {
        a0[kk] = ld8(Wp + (size_t)(wavebase +      lrow)*KK + kk*32 + koff);
        a1[kk] = ld8(Wp + (size_t)(wavebase + 16 + lrow)*KK + kk*32 + koff);
    }

    float bi[4], bf_[4], bg[4], bo[4], c[4], hv[4];
#pragma unroll
    for (int r = 0; r < 4; ++r) {
        int hg = hbase + r;
        bi[r] = bias[hg];       bf_[r] = bias[256+hg];
        bg[r] = bias[512+hg];   bo[r]  = bias[768+hg];
        c[r]  = c0_in[(size_t)L*8192 + fb*256 + hg];
        hv[r] = 0.f;
    }

    int* flags0 = (int*)(ws + O_D0);
    int* flags1 = (int*)(ws + O_D1);
    int* myflag = (L ? flags1 : flags0) + j;

    const unsigned short* xb = (const unsigned short*)(ws + O_XBF) + fb*64  + koff;
    const unsigned short* hb = (const unsigned short*)(ws + O_H0)  + fb*256 + koff;
    const unsigned short* xh = (const unsigned short*)(ws + O_XH1) + fb*512 + koff;

    // per-step 8B store destinations (agent-scope sc1 -> LLC)
    unsigned long long* stA;                 // lanes<32
    unsigned long long* stB = nullptr;       // lanes>=32 (L0: y0 copy)
    if (L == 0) {
        stA = (unsigned long long*)((unsigned short*)(ws + O_H0)  + (size_t)8192 + fb*256 + hbase);
        stB = (unsigned long long*)((unsigned short*)(ws + O_XH1) + (size_t)fb*512 + hbase);
    } else {
        stA = (unsigned long long*)((unsigned short*)(ws + O_XH1) + (size_t)16384 + fb*512 + 256 + hbase);
    }

    for (int t = 0; t < TT; ++t) {
        f32x4 A0 = {0.f,0.f,0.f,0.f}, A1 = {0.f,0.f,0.f,0.f};

        if (L == 0) {
            // x-part: static input -> load + 4 MFMAs BEFORE the poll
            short8 bx0 = ld8(xb), bx1 = ld8(xb + 32);
            A0 = __builtin_amdgcn_mfma_f32_16x16x32_bf16(a0[0], bx0, A0, 0,0,0);
            A1 = __builtin_amdgcn_mfma_f32_16x16x32_bf16(a1[0], bx0, A1, 0,0,0);
            A0 = __builtin_amdgcn_mfma_f32_16x16x32_bf16(a0[1], bx1, A0, 0,0,0);
            A1 = __builtin_amdgcn_mfma_f32_16x16x32_bf16(a1[1], bx1, A1, 0,0,0);

            if (wv == 0) pollLine(flags0, t, lane);   // h0[t] ready (all 8 slices)
            __syncthreads();

            short8 b[8];
#pragma unroll
            for (int kk = 0; kk < 8; ++kk) b[kk] = ld8(hb + 32*kk);
#pragma unroll
            for (int kk = 0; kk < 8; ++kk) {
                A0 = __builtin_amdgcn_mfma_f32_16x16x32_bf16(a0[2+kk], b[kk], A0, 0,0,0);
                A1 = __builtin_amdgcn_mfma_f32_16x16x32_bf16(a1[2+kk], b[kk], A1, 0,0,0);
            }
        } else {
            // y0[t] needs flags0 >= t+1 ; h1[t] needs flags1 >= t (one poll)
            if (wv == 0) pollTwo(flags0, t+1, flags1, t, lane);
            __syncthreads();

            short8 b[8];
#pragma unroll
            for (int kk = 0; kk < 8; ++kk) b[kk] = ld8(xh + 32*kk);        // y0: k 0..255
#pragma unroll
            for (int kk = 0; kk < 8; ++kk) {
                A0 = __builtin_amdgcn_mfma_f32_16x16x32_bf16(a0[kk], b[kk], A0, 0,0,0);
                A1 = __builtin_amdgcn_mfma_f32_16x16x32_bf16(a1[kk], b[kk], A1, 0,0,0);
            }
#pragma unroll
            for (int kk = 0; kk < 8; ++kk) b[kk] = ld8(xh + 256 + 32*kk);  // h1: k 256..511
#pragma unroll
            for (int kk = 0; kk < 8; ++kk) {
                A0 = __builtin_amdgcn_mfma_f32_16x16x32_bf16(a0[8+kk], b[kk], A0, 0,0,0);
                A1 = __builtin_amdgcn_mfma_f32_16x16x32_bf16(a1[8+kk], b[kk], A1, 0,0,0);
            }
        }

        // --- register combine: swap lane<->lane+32 pairs (i,f) and (g,o) ---
#pragma unroll
        for (int r = 0; r < 4; ++r) {
            float x0 = A0[r], y0 = __shfl_xor(x0, 32, 64);
            float x1 = A1[r], y1 = __shfl_xor(x1, 32, 64);
            float gi = (lo ? x0 : y0) + bi[r];
            float gf = (lo ? y0 : x0) + bf_[r];
            float gg = (lo ? x1 : y1) + bg[r];
            float go = (lo ? y1 : x1) + bo[r];
            float iv = sigm_(gi), fv = sigm_(gf), gv = tanhf_(gg), ov = sigm_(go);
            c[r]  = fv*c[r] + iv*gv;
            hv[r] = ov * tanhf_(c[r]);
        }

        unsigned long long w =
            (unsigned long long)pack2(hv[0], hv[1]) |
            ((unsigned long long)pack2(hv[2], hv[3]) << 32);

        if (L == 0) {
            if (lo) __hip_atomic_store(stA, w, __ATOMIC_RELAXED, __HIP_MEMORY_SCOPE_AGENT);
            else    __hip_atomic_store(stB, w, __ATOMIC_RELAXED, __HIP_MEMORY_SCOPE_AGENT);
        } else {
            if (lo) __hip_atomic_store(stA, w, __ATOMIC_RELAXED, __HIP_MEMORY_SCOPE_AGENT);
        }

        // barrier drains every wave's vmcnt (stores LLC-visible) before flag
        __syncthreads();
        if (tid == 0)
            __hip_atomic_store(myflag, t+1, __ATOMIC_RELAXED, __HIP_MEMORY_SCOPE_AGENT);

        xb += 2048; hb += 8192; xh += 16384;
        stA += (L ? 4096 : 2048);
        if (L == 0) stB += 4096;
    }

    if (lo) {
#pragma unroll
        for (int r = 0; r < 4; ++r) {
            out[HN_OFF + (size_t)L*8192 + fb*256 + hbase + r] = hv[r];
            out[CN_OFF + (size_t)L*8192 + fb*256 + hbase + r] = c[r];
        }
    }
}

__global__ __launch_bounds__(512, 2) void lstm_fused(char* ws,
                                                     const float* __restrict__ c0_in,
                                                     float* __restrict__ out)
{
    if (blockIdx.x < NBLK) lstm_body<0>(blockIdx.x, ws, c0_in, out);
    else                   lstm_body<1>(blockIdx.x - NBLK, ws, c0_in, out);
}

// ---------------------------------------------------------------------------
// Fused dense head (reads y1 = xh1[t+1][b][256:512] bf16).
// ---------------------------------------------------------------------------
__global__ __launch_bounds__(256) void head_kernel(const char* __restrict__ ws,
    const float* __restrict__ bd0, const float* __restrict__ bd1,
    const float* __restrict__ bout, float* __restrict__ out)
{
    const __hip_bfloat16* xh1 = (const __hip_bfloat16*)(ws + O_XH1);
    const float* Wd0T  = (const float*)(ws + O_WD0T);
    const float* Wd1T  = (const float*)(ws + O_WD1T);
    const float* WoutT = (const float*)(ws + O_WOUT);

    __shared__ float buf0[16][256];
    __shared__ float buf1[16][256];
    const int row0 = blockIdx.x * 16;
    const int tid = threadIdx.x;

#pragma unroll
    for (int i = 0; i < 16; ++i) {
        int r = row0 + i;
        int b = r >> 11, t = r & 2047;
        buf0[i][tid] = __bfloat162float(xh1[(size_t)(t+1)*16384 + b*512 + 256 + tid]);
    }
    __syncthreads();

    {   // stage 1: Linear+ReLU
        float acc[16];
        float bv = bd0[tid];
#pragma unroll
        for (int r = 0; r < 16; ++r) acc[r] = bv;
        for (int h = 0; h < 256; ++h) {
            float w = Wd0T[h*256 + tid];
#pragma unroll
            for (int r = 0; r < 16; ++r) acc[r] += w * buf0[r][h];
        }
        __syncthreads();
#pragma unroll
        for (int r = 0; r < 16; ++r) buf1[r][tid] = fmaxf(acc[r], 0.0f);
    }
    __syncthreads();

    {   // stage 2: Linear+ReLU
        float acc[16];
        float bv = bd1[tid];
#pragma unroll
        for (int r = 0; r < 16; ++r) acc[r] = bv;
        for (int h = 0; h < 256; ++h) {
            float w = Wd1T[h*256 + tid];
#pragma unroll
            for (int r = 0; r < 16; ++r) acc[r] += w * buf1[r][h];
        }
        __syncthreads();
#pragma unroll
        for (int r = 0; r < 16; ++r) buf0[r][tid] = fmaxf(acc[r], 0.0f);
    }
    __syncthreads();

    {   // stage 3: output Linear
        const int o = tid & 31;
        const int rr = tid >> 5;
        float a0 = bout[o], a1 = bout[o];
        for (int h = 0; h < 256; ++h) {
            float w = WoutT[h*32 + o];
            a0 += w * buf0[rr*2 + 0][h];
            a1 += w * buf0[rr*2 + 1][h];
        }
        out[(size_t)(row0 + rr*2 + 0)*32 + o] = a0;
        out[(size_t)(row0 + rr*2 + 1)*32 + o] = a1;
    }
}

// ---------------------------------------------------------------------------
extern "C" void kernel_launch(void* const* d_in, const int* in_sizes, int n_in,
                              void* d_out, int out_size, void* d_ws, size_t ws_size,
                              hipStream_t stream) {
    const float* x    = (const float*)d_in[0];
    const float* h0   = (const float*)d_in[1];
    const float* c0   = (const float*)d_in[2];
    const float* Wih0 = (const float*)d_in[3];
    const float* Whh0 = (const float*)d_in[4];
    const float* bih0 = (const float*)d_in[5];
    const float* bhh0 = (const float*)d_in[6];
    const float* Wih1 = (const float*)d_in[7];
    const float* Whh1 = (const float*)d_in[8];
    const float* bih1 = (const float*)d_in[9];
    const float* bhh1 = (const float*)d_in[10];
    const float* Wd0  = (const float*)d_in[11];
    const float* bd0  = (const float*)d_in[12];
    const float* Wd1  = (const float*)d_in[13];
    const float* bd1  = (const float*)d_in[14];
    const float* Wout = (const float*)d_in[15];
    const float* bout = (const float*)d_in[16];

    char* ws = (char*)d_ws;
    float* out = (float*)d_out;

    prep_kernel<<<20344, 256, 0, stream>>>(x, h0, Wih0, Whh0, bih0, bhh0,
                                           Wih1, Whh1, bih1, bhh1,
                                           Wd0, Wd1, Wout, ws);
    lstm_fused<<<2*NBLK, 512, 0, stream>>>(ws, c0, out);
    head_kernel<<<4096, 256, 0, stream>>>(ws, bd0, bd1, bout, out);
}